// Round 4
// baseline (469.983 us; speedup 1.0000x reference)
//
#include <hip/hip_runtime.h>

// S=1024, B=8, D=768, H=12, DH=64, PROMPT_NUM=8 (tokens=1016). I/O fp32.
// bf16 MFMA compute, fp32 accum. Attention computes S^T = K*Q^T so the QK^T
// accumulator (C-layout: row=key, col=query) IS the B-fragment of a 16x16x16
// PV MFMA — P never leaves registers (no LDS, no shuffles, no barriers in the
// flash loop). Fixed-shift softmax exp(s-10): scores bounded ~8, masked
// entries exactly 0 either way.

typedef unsigned short u16;
typedef __attribute__((ext_vector_type(8))) short short8;    // 8 bf16 (K=32 A/B frag)
typedef __attribute__((ext_vector_type(4))) short short4v;   // 4 bf16 (K=16 A/B frag)
typedef __attribute__((ext_vector_type(4))) float floatx4;   // MFMA C/D frag
typedef __attribute__((ext_vector_type(4))) unsigned short ushort4v;

#define NB 8
#define NS 1024
#define NH 12
#define ND 768
#define DHD 64
#define TOKENS 1016
#define QKV_OUT_STRIDE 6291456  // S*B*D elements per output tensor

#if __has_builtin(__builtin_amdgcn_exp2f)
#define EXP2(x) __builtin_amdgcn_exp2f(x)
#else
#define EXP2(x) exp2f(x)
#endif

#if __has_builtin(__builtin_amdgcn_mfma_f32_16x16x16bf16_1k)
#define MFMA16(a, b, c) __builtin_amdgcn_mfma_f32_16x16x16bf16_1k(a, b, c, 0, 0, 0)
#define HAVE_M16 1
#elif __has_builtin(__builtin_amdgcn_mfma_f32_16x16x16_bf16)
#define MFMA16(a, b, c) __builtin_amdgcn_mfma_f32_16x16x16_bf16(a, b, c, 0, 0, 0)
#define HAVE_M16 1
#else
#define HAVE_M16 0
#endif

__device__ __forceinline__ u16 f2bf(float f) {
  union { float f; unsigned u; } c; c.f = f;
  return (u16)((c.u + 0x7fffu + ((c.u >> 16) & 1u)) >> 16);  // RNE
}

// ---------------------------------------------------------------------------
// Kernel 0: fp32 -> bf16 for X, in_proj_weight, out_w. 4 elems/thread.
// ---------------------------------------------------------------------------
#define CVT_B0 6144   // X:  6291456/1024
#define CVT_B1 1728   // W:  1769472/1024
#define CVT_B2 576    // Ow: 589824/1024
__global__ __launch_bounds__(256) void cvt3(
    const float* __restrict__ s0, u16* __restrict__ d0,
    const float* __restrict__ s1, u16* __restrict__ d1,
    const float* __restrict__ s2, u16* __restrict__ d2) {
  int blk = blockIdx.x;
  const float* s; u16* d;
  if (blk < CVT_B0) { s = s0; d = d0; }
  else if (blk < CVT_B0 + CVT_B1) { s = s1; d = d1; blk -= CVT_B0; }
  else { s = s2; d = d2; blk -= CVT_B0 + CVT_B1; }
  const int i = (blk * 256 + (int)threadIdx.x) * 4;
  const float4 v = *(const float4*)(s + i);
  ushort4v o;
  o.x = f2bf(v.x); o.y = f2bf(v.y); o.z = f2bf(v.z); o.w = f2bf(v.w);
  *(ushort4v*)(d + i) = o;
}

// ---------------------------------------------------------------------------
// Kernel 1: QKV projection. 128x128 tile/WG, 4 waves, 4x4 of 16x16x32 MFMA.
// ---------------------------------------------------------------------------
__global__ __launch_bounds__(256) void qkv_gemm(
    const u16* __restrict__ Xb, const u16* __restrict__ Wb,
    const float* __restrict__ bias, float* __restrict__ out) {
  __shared__ __align__(16) u16 As[128][40];
  __shared__ __align__(16) u16 Bs[128][40];
  const int tid = threadIdx.x;
  const int lane = tid & 63, wave = tid >> 6;
  const int l15 = lane & 15, quad = lane >> 4;
  const int wm = wave & 1, wn = wave >> 1;
  const int mblk = blockIdx.x * 128;
  const int nblk = blockIdx.y * 128;

  floatx4 acc[4][4];
#pragma unroll
  for (int i = 0; i < 4; ++i)
#pragma unroll
    for (int j = 0; j < 4; ++j) acc[i][j] = (floatx4)0.f;

  const int sr = tid >> 2;
  const int sc = (tid & 3) * 8;

  for (int kt = 0; kt < 24; ++kt) {
    const int k0 = kt * 32;
#pragma unroll
    for (int i = 0; i < 2; ++i) {
      const int r = sr + i * 64;
      const int gm = mblk + r;
      const int b = gm >> 10, s = gm & 1023;
      *(short8*)&As[r][sc] = *(const short8*)(Xb + (s * NB + b) * ND + k0 + sc);
      const int gn = nblk + r;
      *(short8*)&Bs[r][sc] = *(const short8*)(Wb + gn * ND + k0 + sc);
    }
    __syncthreads();
    short8 af[4], bfr[4];
#pragma unroll
    for (int mt = 0; mt < 4; ++mt)
      af[mt] = *(const short8*)&As[wm * 64 + mt * 16 + l15][quad * 8];
#pragma unroll
    for (int nt = 0; nt < 4; ++nt)
      bfr[nt] = *(const short8*)&Bs[wn * 64 + nt * 16 + l15][quad * 8];
#pragma unroll
    for (int mt = 0; mt < 4; ++mt)
#pragma unroll
      for (int nt = 0; nt < 4; ++nt)
        acc[mt][nt] = __builtin_amdgcn_mfma_f32_16x16x32_bf16(
            af[mt], bfr[nt], acc[mt][nt], 0, 0, 0);
    __syncthreads();
  }

#pragma unroll
  for (int mt = 0; mt < 4; ++mt) {
#pragma unroll
    for (int r = 0; r < 4; ++r) {
      const int gm = mblk + wm * 64 + mt * 16 + quad * 4 + r;
      const int b = gm >> 10, s = gm & 1023;
#pragma unroll
      for (int nt = 0; nt < 4; ++nt) {
        const int gn = nblk + wn * 64 + nt * 16 + l15;
        const int seg = gn / ND;
        const int nn = gn - seg * ND;
        out[seg * QKV_OUT_STRIDE + (s * NB + b) * ND + nn] = acc[mt][nt][r] + bias[gn];
      }
    }
  }
}

// ---------------------------------------------------------------------------
// Kernel 1b: prep. z=0: K fp32 -> Kb[b,h,s,c] bf16. z=1: V -> Vt[b,h,c,s].
// ---------------------------------------------------------------------------
__global__ __launch_bounds__(256) void prep(
    const float* __restrict__ K, const float* __restrict__ V,
    u16* __restrict__ Kb, u16* __restrict__ Vt) {
  __shared__ u16 tile[DHD][40];
  const int t = threadIdx.x;
  const int bh = blockIdx.y;
  const int b = bh / NH, h = bh % NH;
  const int s0 = blockIdx.x * 32;
  const int sl = t >> 3;
  const int c0 = (t & 7) * 8;
  const int s = s0 + sl;
  if (blockIdx.z == 0) {
    const float* src = K + ((s * NB + b) * NH + h) * DHD + c0;
    const float4 v0 = *(const float4*)src;
    const float4 v1 = *(const float4*)(src + 4);
    short8 o;
    o[0] = f2bf(v0.x); o[1] = f2bf(v0.y); o[2] = f2bf(v0.z); o[3] = f2bf(v0.w);
    o[4] = f2bf(v1.x); o[5] = f2bf(v1.y); o[6] = f2bf(v1.z); o[7] = f2bf(v1.w);
    *(short8*)(Kb + ((size_t)bh * NS + s) * DHD + c0) = o;
  } else {
    const float* src = V + ((s * NB + b) * NH + h) * DHD + c0;
    const float4 v0 = *(const float4*)src;
    const float4 v1 = *(const float4*)(src + 4);
    tile[c0 + 0][sl] = f2bf(v0.x); tile[c0 + 1][sl] = f2bf(v0.y);
    tile[c0 + 2][sl] = f2bf(v0.z); tile[c0 + 3][sl] = f2bf(v0.w);
    tile[c0 + 4][sl] = f2bf(v1.x); tile[c0 + 5][sl] = f2bf(v1.y);
    tile[c0 + 6][sl] = f2bf(v1.z); tile[c0 + 7][sl] = f2bf(v1.w);
    __syncthreads();
    const int c = t >> 2;
    const int so = (t & 3) * 8;
    *(short8*)(Vt + ((size_t)bh * DHD + c) * NS + s0 + so) =
        *(const short8*)&tile[c][so];
  }
}

// ---------------------------------------------------------------------------
// Kernel 2: flash attention, register-only P path.
// One WG = 64 q of one (b,h); 4 waves x 16 q. 64 iterations of 16 keys:
//   S^T tile = mfma32(K-frag, Q-frag)   (C row=key, col=q)
//   p = exp2(fma(s, C1, C0)); mask tile 63 quad>=2
//   pack -> short4v == B-frag of 16x16x16; O^T[g] = mfma16(Vt-frag, p, O^T[g])
// ---------------------------------------------------------------------------
#if HAVE_M16
__global__ __launch_bounds__(256) void attn(
    const float* __restrict__ Q, const u16* __restrict__ Kb,
    const u16* __restrict__ Vt, u16* __restrict__ mix) {
  const int tid = threadIdx.x;
  const int lane = tid & 63, wave = tid >> 6;
  const int l15 = lane & 15, quad = lane >> 4;
  const int bh = blockIdx.y;
  const int b = bh / NH, h = bh % NH;
  const int q = blockIdx.x * 64 + wave * 16 + l15;

  // Q B-frag: n=l15 -> q, k=quad*8+j -> channel
  const float* qp = Q + ((q * NB + b) * NH + h) * DHD + quad * 8;
  short8 qf0, qf1;
#pragma unroll
  for (int j = 0; j < 8; ++j) {
    qf0[j] = (short)f2bf(qp[j]);
    qf1[j] = (short)f2bf(qp[32 + j]);
  }

  floatx4 O[4];
#pragma unroll
  for (int g = 0; g < 4; ++g) O[g] = (floatx4)0.f;
  float li = 0.f;

  const u16* kbase = Kb + (size_t)bh * NS * DHD;
  const u16* vbase = Vt + (size_t)bh * DHD * NS + quad * 4;
  const bool qmask = (q == 0 || q >= TOKENS);

  const float C1 = 0.125f * 1.44269504089f;   // 1/sqrt(64) * log2(e)
  const float C0 = -10.0f * 1.44269504089f;

  for (int kb = 0; kb < 64; ++kb) {
    const u16* kp = kbase + (kb * 16 + l15) * DHD + quad * 8;
    const short8 kf0 = *(const short8*)kp;
    const short8 kf1 = *(const short8*)(kp + 32);
    floatx4 a = (floatx4)0.f;
    a = __builtin_amdgcn_mfma_f32_16x16x32_bf16(kf0, qf0, a, 0, 0, 0);
    a = __builtin_amdgcn_mfma_f32_16x16x32_bf16(kf1, qf1, a, 0, 0, 0);
    float p[4];
#pragma unroll
    for (int r = 0; r < 4; ++r) p[r] = EXP2(fmaf(a[r], C1, C0));
    if (kb == 63 && quad >= 2 && qmask) {   // keys 1016..1023
#pragma unroll
      for (int r = 0; r < 4; ++r) p[r] = 0.f;
    }
    li += (p[0] + p[1]) + (p[2] + p[3]);
    short4v pb;
#pragma unroll
    for (int r = 0; r < 4; ++r) pb[r] = (short)f2bf(p[r]);
    const u16* vp = vbase + kb * 16;
#pragma unroll
    for (int g = 0; g < 4; ++g) {
      const short4v vf = *(const short4v*)(vp + (g * 16 + l15) * NS);
      O[g] = MFMA16(vf, pb, O[g]);
    }
  }

  li += __shfl_xor(li, 16);
  li += __shfl_xor(li, 32);
  const float rl = 1.0f / li;

  // O^T C-layout: row=quad*4+r -> c=g*16+quad*4+r, col=l15 -> q
  u16* mp = mix + ((size_t)b * NS + q) * ND + h * DHD + quad * 4;
#pragma unroll
  for (int g = 0; g < 4; ++g) {
    ushort4v o;
#pragma unroll
    for (int r = 0; r < 4; ++r) o[r] = f2bf(O[g][r] * rl);
    *(ushort4v*)(mp + g * 16) = o;
  }
}
#else  // fallback: R2 LDS-roundtrip version (compile-safety if _1k absent)
__global__ __launch_bounds__(256) void attn(
    const float* __restrict__ Q, const u16* __restrict__ Kb,
    const u16* __restrict__ Vt, u16* __restrict__ mix) {
  __shared__ __align__(16) u16 Ps[4][16][40];
  const int tid = threadIdx.x;
  const int lane = tid & 63, wave = tid >> 6;
  const int l15 = lane & 15, quad = lane >> 4;
  const int bh = blockIdx.y;
  const int b = bh / NH, h = bh % NH;
  const int qbase = blockIdx.x * 64 + wave * 16;
  const int qrow = qbase + l15;
  const float* qp = Q + ((qrow * NB + b) * NH + h) * DHD + quad * 8;
  short8 qf0, qf1;
#pragma unroll
  for (int j = 0; j < 8; ++j) {
    qf0[j] = (short)f2bf(qp[j]);
    qf1[j] = (short)f2bf(qp[32 + j]);
  }
  floatx4 O[4];
#pragma unroll
  for (int g = 0; g < 4; ++g) O[g] = (floatx4)0.f;
  float li[4] = {0.f, 0.f, 0.f, 0.f};
  const int qr0 = qbase + quad * 4;
  const u16* kbase = Kb + (size_t)bh * NS * DHD;
  const u16* vbase = Vt + (size_t)bh * DHD * NS;
  const float C1 = 0.125f * 1.44269504089f;
  const float C0 = -10.0f * 1.44269504089f;
  for (int kb = 0; kb < 32; ++kb) {
    floatx4 p[2];
#pragma unroll
    for (int t = 0; t < 2; ++t) {
      const int kn = kb * 32 + t * 16 + l15;
      const u16* kp = kbase + kn * DHD;
      const short8 kf0 = *(const short8*)(kp + quad * 8);
      const short8 kf1 = *(const short8*)(kp + 32 + quad * 8);
      floatx4 a = (floatx4)0.f;
      a = __builtin_amdgcn_mfma_f32_16x16x32_bf16(qf0, kf0, a, 0, 0, 0);
      a = __builtin_amdgcn_mfma_f32_16x16x32_bf16(qf1, kf1, a, 0, 0, 0);
#pragma unroll
      for (int r = 0; r < 4; ++r) p[t][r] = EXP2(fmaf(a[r], C1, C0));
    }
    if (kb == 31 && l15 >= 8) {
#pragma unroll
      for (int r = 0; r < 4; ++r) {
        const int qr = qr0 + r;
        if (qr == 0 || qr >= TOKENS) p[1][r] = 0.f;
      }
    }
#pragma unroll
    for (int r = 0; r < 4; ++r) li[r] += p[0][r] + p[1][r];
#pragma unroll
    for (int t = 0; t < 2; ++t)
#pragma unroll
      for (int r = 0; r < 4; ++r)
        Ps[wave][quad * 4 + r][t * 16 + l15] = f2bf(p[t][r]);
    const short8 pf = *(const short8*)&Ps[wave][l15][quad * 8];
#pragma unroll
    for (int g = 0; g < 4; ++g) {
      const short8 vf = *(const short8*)(vbase + (g * 16 + l15) * NS + kb * 32 + quad * 8);
      O[g] = __builtin_amdgcn_mfma_f32_16x16x32_bf16(pf, vf, O[g], 0, 0, 0);
    }
  }
#pragma unroll
  for (int off = 1; off < 16; off <<= 1)
#pragma unroll
    for (int r = 0; r < 4; ++r) li[r] += __shfl_xor(li[r], off, 16);
#pragma unroll
  for (int r = 0; r < 4; ++r) {
    const float rl = 1.0f / li[r];
    const int qr = qr0 + r;
#pragma unroll
    for (int g = 0; g < 4; ++g)
      mix[(b * NS + qr) * ND + h * DHD + g * 16 + l15] = f2bf(O[g][r] * rl);
  }
}
#endif

// ---------------------------------------------------------------------------
// Kernel 3: out projection, fp32 output to (S,B,D).
// ---------------------------------------------------------------------------
__global__ __launch_bounds__(256) void out_gemm(
    const u16* __restrict__ A, const u16* __restrict__ Wb,
    const float* __restrict__ bias, float* __restrict__ out) {
  __shared__ __align__(16) u16 As[128][40];
  __shared__ __align__(16) u16 Bs[128][40];
  const int tid = threadIdx.x;
  const int lane = tid & 63, wave = tid >> 6;
  const int l15 = lane & 15, quad = lane >> 4;
  const int wm = wave & 1, wn = wave >> 1;
  const int mblk = blockIdx.x * 128;
  const int nblk = blockIdx.y * 128;

  floatx4 acc[4][4];
#pragma unroll
  for (int i = 0; i < 4; ++i)
#pragma unroll
    for (int j = 0; j < 4; ++j) acc[i][j] = (floatx4)0.f;

  const int sr = tid >> 2;
  const int sc = (tid & 3) * 8;

  for (int kt = 0; kt < 24; ++kt) {
    const int k0 = kt * 32;
#pragma unroll
    for (int i = 0; i < 2; ++i) {
      const int r = sr + i * 64;
      *(short8*)&As[r][sc] = *(const short8*)(A + (mblk + r) * ND + k0 + sc);
      *(short8*)&Bs[r][sc] = *(const short8*)(Wb + (nblk + r) * ND + k0 + sc);
    }
    __syncthreads();
    short8 af[4], bfr[4];
#pragma unroll
    for (int mt = 0; mt < 4; ++mt)
      af[mt] = *(const short8*)&As[wm * 64 + mt * 16 + l15][quad * 8];
#pragma unroll
    for (int nt = 0; nt < 4; ++nt)
      bfr[nt] = *(const short8*)&Bs[wn * 64 + nt * 16 + l15][quad * 8];
#pragma unroll
    for (int mt = 0; mt < 4; ++mt)
#pragma unroll
      for (int nt = 0; nt < 4; ++nt)
        acc[mt][nt] = __builtin_amdgcn_mfma_f32_16x16x32_bf16(
            af[mt], bfr[nt], acc[mt][nt], 0, 0, 0);
    __syncthreads();
  }

#pragma unroll
  for (int mt = 0; mt < 4; ++mt) {
#pragma unroll
    for (int r = 0; r < 4; ++r) {
      const int gm = mblk + wm * 64 + mt * 16 + quad * 4 + r;
      const int b = gm >> 10, s = gm & 1023;
#pragma unroll
      for (int nt = 0; nt < 4; ++nt) {
        const int gn = nblk + wn * 64 + nt * 16 + l15;
        out[(s * NB + b) * ND + gn] = acc[mt][nt][r] + bias[gn];
      }
    }
  }
}

extern "C" void kernel_launch(void* const* d_in, const int* in_sizes, int n_in,
                              void* d_out, int out_size, void* d_ws, size_t ws_size,
                              hipStream_t stream) {
  const float* X  = (const float*)d_in[0];
  const float* W  = (const float*)d_in[1];
  const float* Bi = (const float*)d_in[2];
  const float* Ow = (const float*)d_in[3];
  const float* Ob = (const float*)d_in[4];
  float* out = (float*)d_out;   // [q | k | v | out], each S*B*D fp32

  u16* Xb  = (u16*)d_ws;            // 6291456
  u16* Wb  = Xb  + 6291456;         // 1769472
  u16* Owb = Wb  + 1769472;         // 589824
  u16* Vt  = Owb + 589824;          // 6291456  (b,h,c,s)
  u16* Kb  = Vt  + 6291456;         // 6291456  (b,h,s,c)
  u16* mix = Kb  + 6291456;         // 6291456  (b,s,d)

  cvt3<<<CVT_B0 + CVT_B1 + CVT_B2, 256, 0, stream>>>(X, Xb, W, Wb, Ow, Owb);
  qkv_gemm<<<dim3(64, 18), 256, 0, stream>>>(Xb, Wb, Bi, out);
  prep<<<dim3(32, 96, 2), 256, 0, stream>>>(out + QKV_OUT_STRIDE,
                                            out + 2 * QKV_OUT_STRIDE, Kb, Vt);
  attn<<<dim3(16, 96), 256, 0, stream>>>(out, Kb, Vt, mix);
  out_gemm<<<dim3(64, 6), 256, 0, stream>>>(mix, Owb, Ob, out + 3 * QKV_OUT_STRIDE);
}

// Round 6
// 263.729 us; speedup vs baseline: 1.7821x; 1.7821x over previous
//
#include <hip/hip_runtime.h>

// S=1024, B=8, D=768, H=12, DH=64, PROMPT_NUM=8 (tokens=1016). I/O fp32.
// bf16 MFMA compute, fp32 accum. Attention: S^T = K*Q^T so the QK accumulator
// (row=key, col=q) IS the B-fragment of the 16x16x16 PV MFMA (P stays in
// registers). K/V tiles staged cooperatively in LDS (once per WG), reg-
// buffered prefetch pipeline, 32 q/wave.
// NOTE: MFMA16 must be gated on __HIP_DEVICE_COMPILE__ — the host pass's
// __has_builtin() returns false for amdgcn builtins (R4 compile failure).

typedef unsigned short u16;
typedef __attribute__((ext_vector_type(8))) short short8;    // 8 bf16 (K=32 frag)
typedef __attribute__((ext_vector_type(4))) short short4v;   // 4 bf16 (K=16 frag)
typedef __attribute__((ext_vector_type(4))) float floatx4;   // MFMA C/D frag
typedef __attribute__((ext_vector_type(4))) unsigned short ushort4v;

#define NB 8
#define NS 1024
#define NH 12
#define ND 768
#define DHD 64
#define TOKENS 1016
#define QKV_OUT_STRIDE 6291456  // S*B*D elements per output tensor

#if __has_builtin(__builtin_amdgcn_exp2f)
#define EXP2(x) __builtin_amdgcn_exp2f(x)
#else
#define EXP2(x) exp2f(x)
#endif

#if defined(__HIP_DEVICE_COMPILE__)
  #if __has_builtin(__builtin_amdgcn_mfma_f32_16x16x16bf16_1k)
    #define MFMA16(a, b, c) __builtin_amdgcn_mfma_f32_16x16x16bf16_1k(a, b, c, 0, 0, 0)
  #else
    #define MFMA16(a, b, c) __builtin_amdgcn_mfma_f32_16x16x16_bf16(a, b, c, 0, 0, 0)
  #endif
#else
  #define MFMA16(a, b, c) (c)  // host pass: dead code, never executed
#endif

__device__ __forceinline__ u16 f2bf(float f) {
  union { float f; unsigned u; } c; c.f = f;
  return (u16)((c.u + 0x7fffu + ((c.u >> 16) & 1u)) >> 16);  // RNE
}

// ---------------------------------------------------------------------------
// Kernel 0: fp32 -> bf16 for X, in_proj_weight, out_w. 4 elems/thread.
// ---------------------------------------------------------------------------
#define CVT_B0 6144   // X:  6291456/1024
#define CVT_B1 1728   // W:  1769472/1024
#define CVT_B2 576    // Ow: 589824/1024
__global__ __launch_bounds__(256) void cvt3(
    const float* __restrict__ s0, u16* __restrict__ d0,
    const float* __restrict__ s1, u16* __restrict__ d1,
    const float* __restrict__ s2, u16* __restrict__ d2) {
  int blk = blockIdx.x;
  const float* s; u16* d;
  if (blk < CVT_B0) { s = s0; d = d0; }
  else if (blk < CVT_B0 + CVT_B1) { s = s1; d = d1; blk -= CVT_B0; }
  else { s = s2; d = d2; blk -= CVT_B0 + CVT_B1; }
  const int i = (blk * 256 + (int)threadIdx.x) * 4;
  const float4 v = *(const float4*)(s + i);
  ushort4v o;
  o.x = f2bf(v.x); o.y = f2bf(v.y); o.z = f2bf(v.z); o.w = f2bf(v.w);
  *(ushort4v*)(d + i) = o;
}

// ---------------------------------------------------------------------------
// Kernel 1: QKV projection. 128x128 tile/WG, 4 waves, 4x4 of 16x16x32 MFMA.
// ---------------------------------------------------------------------------
__global__ __launch_bounds__(256) void qkv_gemm(
    const u16* __restrict__ Xb, const u16* __restrict__ Wb,
    const float* __restrict__ bias, float* __restrict__ out) {
  __shared__ __align__(16) u16 As[128][40];
  __shared__ __align__(16) u16 Bs[128][40];
  const int tid = threadIdx.x;
  const int lane = tid & 63, wave = tid >> 6;
  const int l15 = lane & 15, quad = lane >> 4;
  const int wm = wave & 1, wn = wave >> 1;
  const int mblk = blockIdx.x * 128;
  const int nblk = blockIdx.y * 128;

  floatx4 acc[4][4];
#pragma unroll
  for (int i = 0; i < 4; ++i)
#pragma unroll
    for (int j = 0; j < 4; ++j) acc[i][j] = (floatx4)0.f;

  const int sr = tid >> 2;
  const int sc = (tid & 3) * 8;

  for (int kt = 0; kt < 24; ++kt) {
    const int k0 = kt * 32;
#pragma unroll
    for (int i = 0; i < 2; ++i) {
      const int r = sr + i * 64;
      const int gm = mblk + r;
      const int b = gm >> 10, s = gm & 1023;
      *(short8*)&As[r][sc] = *(const short8*)(Xb + (s * NB + b) * ND + k0 + sc);
      const int gn = nblk + r;
      *(short8*)&Bs[r][sc] = *(const short8*)(Wb + gn * ND + k0 + sc);
    }
    __syncthreads();
    short8 af[4], bfr[4];
#pragma unroll
    for (int mt = 0; mt < 4; ++mt)
      af[mt] = *(const short8*)&As[wm * 64 + mt * 16 + l15][quad * 8];
#pragma unroll
    for (int nt = 0; nt < 4; ++nt)
      bfr[nt] = *(const short8*)&Bs[wn * 64 + nt * 16 + l15][quad * 8];
#pragma unroll
    for (int mt = 0; mt < 4; ++mt)
#pragma unroll
      for (int nt = 0; nt < 4; ++nt)
        acc[mt][nt] = __builtin_amdgcn_mfma_f32_16x16x32_bf16(
            af[mt], bfr[nt], acc[mt][nt], 0, 0, 0);
    __syncthreads();
  }

#pragma unroll
  for (int mt = 0; mt < 4; ++mt) {
#pragma unroll
    for (int r = 0; r < 4; ++r) {
      const int gm = mblk + wm * 64 + mt * 16 + quad * 4 + r;
      const int b = gm >> 10, s = gm & 1023;
#pragma unroll
      for (int nt = 0; nt < 4; ++nt) {
        const int gn = nblk + wn * 64 + nt * 16 + l15;
        const int seg = gn / ND;
        const int nn = gn - seg * ND;
        out[seg * QKV_OUT_STRIDE + (s * NB + b) * ND + nn] = acc[mt][nt][r] + bias[gn];
      }
    }
  }
}

// ---------------------------------------------------------------------------
// Kernel 1b: prep. z=0: K fp32 -> Kb[b,h,s,c] bf16. z=1: V -> Vt[b,h,c,s].
// ---------------------------------------------------------------------------
__global__ __launch_bounds__(256) void prep(
    const float* __restrict__ K, const float* __restrict__ V,
    u16* __restrict__ Kb, u16* __restrict__ Vt) {
  __shared__ u16 tile[DHD][40];
  const int t = threadIdx.x;
  const int bh = blockIdx.y;
  const int b = bh / NH, h = bh % NH;
  const int s0 = blockIdx.x * 32;
  const int sl = t >> 3;
  const int c0 = (t & 7) * 8;
  const int s = s0 + sl;
  if (blockIdx.z == 0) {
    const float* src = K + ((s * NB + b) * NH + h) * DHD + c0;
    const float4 v0 = *(const float4*)src;
    const float4 v1 = *(const float4*)(src + 4);
    short8 o;
    o[0] = f2bf(v0.x); o[1] = f2bf(v0.y); o[2] = f2bf(v0.z); o[3] = f2bf(v0.w);
    o[4] = f2bf(v1.x); o[5] = f2bf(v1.y); o[6] = f2bf(v1.z); o[7] = f2bf(v1.w);
    *(short8*)(Kb + ((size_t)bh * NS + s) * DHD + c0) = o;
  } else {
    const float* src = V + ((s * NB + b) * NH + h) * DHD + c0;
    const float4 v0 = *(const float4*)src;
    const float4 v1 = *(const float4*)(src + 4);
    tile[c0 + 0][sl] = f2bf(v0.x); tile[c0 + 1][sl] = f2bf(v0.y);
    tile[c0 + 2][sl] = f2bf(v0.z); tile[c0 + 3][sl] = f2bf(v0.w);
    tile[c0 + 4][sl] = f2bf(v1.x); tile[c0 + 5][sl] = f2bf(v1.y);
    tile[c0 + 6][sl] = f2bf(v1.z); tile[c0 + 7][sl] = f2bf(v1.w);
    __syncthreads();
    const int c = t >> 2;
    const int so = (t & 3) * 8;
    *(short8*)(Vt + ((size_t)bh * DHD + c) * NS + s0 + so) =
        *(const short8*)&tile[c][so];
  }
}

// ---------------------------------------------------------------------------
// Kernel 2: flash attention. WG = 128 q of one (b,h); wave = 32 q (2 Q frags).
// 16 outer iters of 64-key tiles staged in LDS (loaded once per WG, reg-
// buffered prefetch). Register-only P path:
//   S^T = mfma32(K-frag, Q-frag)  (C row=key, col=q)
//   p = exp2(fma(s,C1,C0)); pack -> short4v = B-frag of 16x16x16
//   O^T[g] = mfma16(V-frag, p, O^T[g])
// ---------------------------------------------------------------------------
__global__ __launch_bounds__(256) void attn(
    const float* __restrict__ Q, const u16* __restrict__ Kb,
    const u16* __restrict__ Vt, u16* __restrict__ mix) {
  __shared__ __align__(16) u16 Kt[64][72];  // [key_local][c]
  __shared__ __align__(16) u16 Vs[64][72];  // [c][key_local]
  const int tid = threadIdx.x;
  const int lane = tid & 63, wave = tid >> 6;
  const int l15 = lane & 15, quad = lane >> 4;
  const int bh = blockIdx.y;
  const int b = bh / NH, h = bh % NH;
  const int qb = blockIdx.x * 128 + wave * 32;

  // Q B-frags: n=l15 -> q, k=quad*8+j -> channel. fp32 -> bf16 once.
  short8 qf[2][2];
  bool qmask[2];
#pragma unroll
  for (int j = 0; j < 2; ++j) {
    const int qj = qb + j * 16 + l15;
    qmask[j] = (qj == 0 || qj >= TOKENS);
    const float* qp = Q + ((qj * NB + b) * NH + h) * DHD + quad * 8;
#pragma unroll
    for (int e = 0; e < 8; ++e) {
      qf[j][0][e] = (short)f2bf(qp[e]);
      qf[j][1][e] = (short)f2bf(qp[32 + e]);
    }
  }

  floatx4 O[2][4];
#pragma unroll
  for (int j = 0; j < 2; ++j)
#pragma unroll
    for (int g = 0; g < 4; ++g) O[j][g] = (floatx4)0.f;
  float li[2] = {0.f, 0.f};

  const u16* kg = Kb + (size_t)bh * NS * DHD;  // rows of 64 shorts (s,c)
  const u16* vg = Vt + (size_t)bh * DHD * NS;  // rows of 1024 shorts (c,s)

  const float C1 = 0.125f * 1.44269504089f;    // 1/sqrt(64) * log2(e)
  const float C0 = -10.0f * 1.44269504089f;

  // staging: thread t covers row t>>2 (0..63), 32B chunk (t&3)*16 shorts
  const int srow = tid >> 2;
  const int scol = (tid & 3) * 16;

  short8 pk0, pk1, pv0, pv1;
  {
    pk0 = *(const short8*)(kg + srow * DHD + scol);
    pk1 = *(const short8*)(kg + srow * DHD + scol + 8);
    pv0 = *(const short8*)(vg + srow * NS + scol);
    pv1 = *(const short8*)(vg + srow * NS + scol + 8);
  }

  for (int it = 0; it < 16; ++it) {
    *(short8*)&Kt[srow][scol] = pk0;
    *(short8*)&Kt[srow][scol + 8] = pk1;
    *(short8*)&Vs[srow][scol] = pv0;
    *(short8*)&Vs[srow][scol + 8] = pv1;
    __syncthreads();
    if (it < 15) {
      const int k0 = (it + 1) * 64;
      pk0 = *(const short8*)(kg + (k0 + srow) * DHD + scol);
      pk1 = *(const short8*)(kg + (k0 + srow) * DHD + scol + 8);
      pv0 = *(const short8*)(vg + srow * NS + k0 + scol);
      pv1 = *(const short8*)(vg + srow * NS + k0 + scol + 8);
    }
    const bool mrow = (it == 15) && (quad >= 2);  // keys >= 1016 rows
#pragma unroll
    for (int sub = 0; sub < 4; ++sub) {
      const short8 kf0 = *(const short8*)&Kt[sub * 16 + l15][quad * 8];
      const short8 kf1 = *(const short8*)&Kt[sub * 16 + l15][32 + quad * 8];
      short4v pb[2];
#pragma unroll
      for (int j = 0; j < 2; ++j) {
        floatx4 a = (floatx4)0.f;
        a = __builtin_amdgcn_mfma_f32_16x16x32_bf16(kf0, qf[j][0], a, 0, 0, 0);
        a = __builtin_amdgcn_mfma_f32_16x16x32_bf16(kf1, qf[j][1], a, 0, 0, 0);
        float p[4];
#pragma unroll
        for (int r = 0; r < 4; ++r) p[r] = EXP2(fmaf(a[r], C1, C0));
        if (sub == 3 && mrow && qmask[j]) {
#pragma unroll
          for (int r = 0; r < 4; ++r) p[r] = 0.f;
        }
        li[j] += (p[0] + p[1]) + (p[2] + p[3]);
#pragma unroll
        for (int r = 0; r < 4; ++r) pb[j][r] = (short)f2bf(p[r]);
      }
#pragma unroll
      for (int g = 0; g < 4; ++g) {
        const short4v vf = *(const short4v*)&Vs[g * 16 + l15][sub * 16 + quad * 4];
        O[0][g] = MFMA16(vf, pb[0], O[0][g]);
        O[1][g] = MFMA16(vf, pb[1], O[1][g]);
      }
    }
    __syncthreads();
  }

#pragma unroll
  for (int j = 0; j < 2; ++j) {
    float l = li[j];
    l += __shfl_xor(l, 16);
    l += __shfl_xor(l, 32);
    const float rl = 1.0f / l;
    const int qj = qb + j * 16 + l15;
    u16* mp = mix + ((size_t)b * NS + qj) * ND + h * DHD + quad * 4;
#pragma unroll
    for (int g = 0; g < 4; ++g) {
      ushort4v o;
#pragma unroll
      for (int r = 0; r < 4; ++r) o[r] = f2bf(O[j][g][r] * rl);
      *(ushort4v*)(mp + g * 16) = o;
    }
  }
}

// ---------------------------------------------------------------------------
// Kernel 3: out projection, fp32 output to (S,B,D).
// ---------------------------------------------------------------------------
__global__ __launch_bounds__(256) void out_gemm(
    const u16* __restrict__ A, const u16* __restrict__ Wb,
    const float* __restrict__ bias, float* __restrict__ out) {
  __shared__ __align__(16) u16 As[128][40];
  __shared__ __align__(16) u16 Bs[128][40];
  const int tid = threadIdx.x;
  const int lane = tid & 63, wave = tid >> 6;
  const int l15 = lane & 15, quad = lane >> 4;
  const int wm = wave & 1, wn = wave >> 1;
  const int mblk = blockIdx.x * 128;
  const int nblk = blockIdx.y * 128;

  floatx4 acc[4][4];
#pragma unroll
  for (int i = 0; i < 4; ++i)
#pragma unroll
    for (int j = 0; j < 4; ++j) acc[i][j] = (floatx4)0.f;

  const int sr = tid >> 2;
  const int sc = (tid & 3) * 8;

  for (int kt = 0; kt < 24; ++kt) {
    const int k0 = kt * 32;
#pragma unroll
    for (int i = 0; i < 2; ++i) {
      const int r = sr + i * 64;
      *(short8*)&As[r][sc] = *(const short8*)(A + (mblk + r) * ND + k0 + sc);
      *(short8*)&Bs[r][sc] = *(const short8*)(Wb + (nblk + r) * ND + k0 + sc);
    }
    __syncthreads();
    short8 af[4], bfr[4];
#pragma unroll
    for (int mt = 0; mt < 4; ++mt)
      af[mt] = *(const short8*)&As[wm * 64 + mt * 16 + l15][quad * 8];
#pragma unroll
    for (int nt = 0; nt < 4; ++nt)
      bfr[nt] = *(const short8*)&Bs[wn * 64 + nt * 16 + l15][quad * 8];
#pragma unroll
    for (int mt = 0; mt < 4; ++mt)
#pragma unroll
      for (int nt = 0; nt < 4; ++nt)
        acc[mt][nt] = __builtin_amdgcn_mfma_f32_16x16x32_bf16(
            af[mt], bfr[nt], acc[mt][nt], 0, 0, 0);
    __syncthreads();
  }

#pragma unroll
  for (int mt = 0; mt < 4; ++mt) {
#pragma unroll
    for (int r = 0; r < 4; ++r) {
      const int gm = mblk + wm * 64 + mt * 16 + quad * 4 + r;
      const int b = gm >> 10, s = gm & 1023;
#pragma unroll
      for (int nt = 0; nt < 4; ++nt) {
        const int gn = nblk + wn * 64 + nt * 16 + l15;
        out[(s * NB + b) * ND + gn] = acc[mt][nt][r] + bias[gn];
      }
    }
  }
}

extern "C" void kernel_launch(void* const* d_in, const int* in_sizes, int n_in,
                              void* d_out, int out_size, void* d_ws, size_t ws_size,
                              hipStream_t stream) {
  const float* X  = (const float*)d_in[0];
  const float* W  = (const float*)d_in[1];
  const float* Bi = (const float*)d_in[2];
  const float* Ow = (const float*)d_in[3];
  const float* Ob = (const float*)d_in[4];
  float* out = (float*)d_out;   // [q | k | v | out], each S*B*D fp32

  u16* Xb  = (u16*)d_ws;            // 6291456
  u16* Wb  = Xb  + 6291456;         // 1769472
  u16* Owb = Wb  + 1769472;         // 589824
  u16* Vt  = Owb + 589824;          // 6291456  (b,h,c,s)
  u16* Kb  = Vt  + 6291456;         // 6291456  (b,h,s,c)
  u16* mix = Kb  + 6291456;         // 6291456  (b,s,d)

  cvt3<<<CVT_B0 + CVT_B1 + CVT_B2, 256, 0, stream>>>(X, Xb, W, Wb, Ow, Owb);
  qkv_gemm<<<dim3(64, 18), 256, 0, stream>>>(Xb, Wb, Bi, out);
  prep<<<dim3(32, 96, 2), 256, 0, stream>>>(out + QKV_OUT_STRIDE,
                                            out + 2 * QKV_OUT_STRIDE, Kb, Vt);
  attn<<<dim3(8, 96), 256, 0, stream>>>(out, Kb, Vt, mix);
  out_gemm<<<dim3(64, 6), 256, 0, stream>>>(mix, Owb, Ob, out + 3 * QKV_OUT_STRIDE);
}